// Round 11
// baseline (463.567 us; speedup 1.0000x reference)
//
#include <hip/hip_runtime.h>
#include <math.h>

#define NNODES_FEAT 128   // node input dim
#define HD 128            // H*D = 4*32
#define H 4
#define D 32
#define EDGE_F 16         // edge input dim
#define NEG_SLOPE 0.2f

typedef _Float16 f16;
typedef _Float16 f16x2 __attribute__((ext_vector_type(2)));
typedef _Float16 f16x4 __attribute__((ext_vector_type(4)));
typedef _Float16 f16x8 __attribute__((ext_vector_type(8)));
typedef float f32x4 __attribute__((ext_vector_type(4)));

union ExPack { float2 f; f16x4 h; };

// ---------------- K0: w_eh[k][h] = sum_d W_edge[k*128 + h*32 + d] * attn_edge[h*32+d]
__global__ void k_wedge(const float* __restrict__ W_edge,
                        const float* __restrict__ attn_edge,
                        float* __restrict__ w_eh) {
    int t = threadIdx.x;            // 0..63
    int k = t >> 2;                 // 0..15
    int h = t & 3;                  // 0..3
    float s = 0.f;
    for (int d = 0; d < D; ++d)
        s += W_edge[k * HD + h * D + d] * attn_edge[h * D + d];
    w_eh[k * H + h] = s;
}

// ---------------- K0c: Wt[n][k] = (n<128 ? Wfc[k][n] : Wres[k][n-128]) as fp16
__global__ __launch_bounds__(256) void k_wt(const float* __restrict__ Wfc,
                                            const float* __restrict__ Wres,
                                            f16* __restrict__ Wt) {
    int i = blockIdx.x * 256 + threadIdx.x;    // 0..32767
    int n = i >> 7, k = i & 127;
    float v = (n < 128) ? Wfc[k * HD + n] : Wres[k * HD + (n - 128)];
    Wt[(size_t)n * 128 + k] = (f16)v;
}

// ---------------- K1: MFMA GEMM, NO LDS / NO BARRIERS.
// A row fragments loaded per-lane from global (L3-resident, 128B segments/row);
// B f16x8 fragments read directly from global (64KB Wt -> L1/L2-hot).
// cb=0 epilogue: feat16 + fused a_src/a_dst. cb=1: res16 (or fp32 out fallback).
__global__ __launch_bounds__(256) void k_gemm_mfma(
    const float* __restrict__ A, const f16* __restrict__ Wt,
    const float* __restrict__ bias, const float* __restrict__ asp,
    const float* __restrict__ adp, f16* __restrict__ feat16,
    float* __restrict__ a_src, float* __restrict__ a_dst,
    f16* __restrict__ res16, float* __restrict__ out, int N) {
    int tid = threadIdx.x;
    int wave = tid >> 6, lane = tid & 63;
    int am = lane & 15, aq = lane >> 4;
    int gr = blockIdx.x * 64 + wave * 16 + am;     // this lane's A row
    int orow0 = blockIdx.x * 64 + wave * 16 + aq * 4;

    // load A row fragment: 32 fp32 (cols kc*32 + aq*8 .. +8) -> f16x8 regs
    f16x8 af[4];
    bool rowok = gr < N;
    const float* Arow = A + (size_t)gr * 128;
#pragma unroll
    for (int kc = 0; kc < 4; ++kc) {
        float4 lo = make_float4(0.f, 0.f, 0.f, 0.f), hi = lo;
        if (rowok) {
            lo = *(const float4*)(Arow + kc * 32 + aq * 8);
            hi = *(const float4*)(Arow + kc * 32 + aq * 8 + 4);
        }
        af[kc] = (f16x8){(f16)lo.x, (f16)lo.y, (f16)lo.z, (f16)lo.w,
                         (f16)hi.x, (f16)hi.y, (f16)hi.z, (f16)hi.w};
    }

    for (int cb = 0; cb < 2; ++cb) {
        const f16* Wblk = Wt + (size_t)cb * 128 * 128;
        f32x4 acc[8];
#pragma unroll
        for (int nt = 0; nt < 8; ++nt) acc[nt] = (f32x4){0.f, 0.f, 0.f, 0.f};
#pragma unroll
        for (int kc = 0; kc < 4; ++kc) {
#pragma unroll
            for (int nt = 0; nt < 8; ++nt) {
                f16x8 b = *(const f16x8*)(Wblk + (size_t)(nt * 16 + am) * 128 + kc * 32 + aq * 8);
                acc[nt] = __builtin_amdgcn_mfma_f32_16x16x32_f16(af[kc], b, acc[nt], 0, 0, 0);
            }
        }

        if (cb == 0) {
            // feat16 store
#pragma unroll
            for (int nt = 0; nt < 8; ++nt) {
                int col = nt * 16 + am;
#pragma unroll
                for (int r = 0; r < 4; ++r) {
                    int row = orow0 + r;
                    if (row < N) feat16[(size_t)row * 128 + col] = (f16)acc[nt][r];
                }
            }
            // fused a_src/a_dst: per-lane partials over cols, xor-reduce over am
            float w1v[8], w2v[8];
#pragma unroll
            for (int nt = 0; nt < 8; ++nt) {
                w1v[nt] = asp[nt * 16 + am];
                w2v[nt] = adp[nt * 16 + am];
            }
#pragma unroll
            for (int r = 0; r < 4; ++r) {
                float p1[4] = {0.f, 0.f, 0.f, 0.f};
                float p2[4] = {0.f, 0.f, 0.f, 0.f};
#pragma unroll
                for (int nt = 0; nt < 8; ++nt) {
                    int h = nt >> 1;
                    p1[h] += acc[nt][r] * w1v[nt];
                    p2[h] += acc[nt][r] * w2v[nt];
                }
#pragma unroll
                for (int off = 1; off < 16; off <<= 1) {
#pragma unroll
                    for (int h = 0; h < 4; ++h) {
                        p1[h] += __shfl_xor(p1[h], off);
                        p2[h] += __shfl_xor(p2[h], off);
                    }
                }
                int row = orow0 + r;
                if (row < N) {
                    if (am < 4) {
                        float v = am == 0 ? p1[0] : am == 1 ? p1[1] : am == 2 ? p1[2] : p1[3];
                        a_src[row * 4 + am] = v;
                    } else if (am < 8) {
                        int hh = am - 4;
                        float v = hh == 0 ? p2[0] : hh == 1 ? p2[1] : hh == 2 ? p2[2] : p2[3];
                        a_dst[row * 4 + hh] = v;
                    }
                }
            }
        } else {
#pragma unroll
            for (int nt = 0; nt < 8; ++nt) {
                int col = nt * 16 + am;
                float bv = bias[col];
#pragma unroll
                for (int r = 0; r < 4; ++r) {
                    int row = orow0 + r;
                    if (row < N) {
                        float v = acc[nt][r] + bv;
                        if (res16) res16[(size_t)row * 128 + col] = (f16)v;
                        else       out[(size_t)row * 128 + col] = v;
                    }
                }
            }
        }
    }
}

// ---------------- K2a: count + rank + FULL edge logit -> exp -> evp[e] (edge order)
// 2 edges/thread; ALL loads (indices, MLP inputs, gathers) issued up front.
__global__ __launch_bounds__(256) void k_edge_logit(
    const float* __restrict__ edge_inputs, const int* __restrict__ src,
    const int* __restrict__ dst, const float* __restrict__ w_eh,
    const float* __restrict__ a_src, const float* __restrict__ a_dst,
    int* __restrict__ deg, int* __restrict__ rank,
    float2* __restrict__ evp, int E) {
    __shared__ float weh_s[EDGE_F * H];
    if (threadIdx.x < EDGE_F * H) weh_s[threadIdx.x] = w_eh[threadIdx.x];
    __syncthreads();

    int base = blockIdx.x * 512 + threadIdx.x;
    int e0 = base, e1 = base + 256;
    bool v0 = e0 < E, v1 = e1 < E;

    // coalesced index loads
    int s0 = v0 ? src[e0] : 0, s1 = v1 ? src[e1] : 0;
    int d0 = v0 ? dst[e0] : 0, d1 = v1 ? dst[e1] : 0;

    // MLP input loads (independent)
    float4 xa[4], xb[4];
    if (v0) {
        const float* x = edge_inputs + (size_t)e0 * EDGE_F;
        xa[0] = *(const float4*)(x);      xa[1] = *(const float4*)(x + 4);
        xa[2] = *(const float4*)(x + 8);  xa[3] = *(const float4*)(x + 12);
    }
    if (v1) {
        const float* x = edge_inputs + (size_t)e1 * EDGE_F;
        xb[0] = *(const float4*)(x);      xb[1] = *(const float4*)(x + 4);
        xb[2] = *(const float4*)(x + 8);  xb[3] = *(const float4*)(x + 12);
    }

    // L2-resident gathers
    float4 as0 = *(const float4*)(a_src + s0 * H);
    float4 ad0 = *(const float4*)(a_dst + d0 * H);
    float4 as1 = *(const float4*)(a_src + s1 * H);
    float4 ad1 = *(const float4*)(a_dst + d1 * H);

    int r0 = v0 ? atomicAdd(deg + d0, 1) : 0;
    int r1 = v1 ? atomicAdd(deg + d1, 1) : 0;

    if (v0) {
        float ae0 = 0.f, ae1 = 0.f, ae2 = 0.f, ae3 = 0.f;
        const float* xs = (const float*)xa;
#pragma unroll
        for (int k = 0; k < EDGE_F; ++k) {
            float xv = xs[k];
            ae0 += xv * weh_s[k * H + 0];
            ae1 += xv * weh_s[k * H + 1];
            ae2 += xv * weh_s[k * H + 2];
            ae3 += xv * weh_s[k * H + 3];
        }
        float ev[H];
        ev[0] = as0.x + ad0.x + ae0;
        ev[1] = as0.y + ad0.y + ae1;
        ev[2] = as0.z + ad0.z + ae2;
        ev[3] = as0.w + ad0.w + ae3;
#pragma unroll
        for (int h = 0; h < H; ++h) {
            float t = ev[h];
            t = t > 0.f ? t : NEG_SLOPE * t;
            ev[h] = __expf(t);
        }
        ExPack p;
        p.h = (f16x4){(f16)ev[0], (f16)ev[1], (f16)ev[2], (f16)ev[3]};
        evp[e0] = p.f;
        rank[e0] = r0;
    }
    if (v1) {
        float ae0 = 0.f, ae1 = 0.f, ae2 = 0.f, ae3 = 0.f;
        const float* xs = (const float*)xb;
#pragma unroll
        for (int k = 0; k < EDGE_F; ++k) {
            float xv = xs[k];
            ae0 += xv * weh_s[k * H + 0];
            ae1 += xv * weh_s[k * H + 1];
            ae2 += xv * weh_s[k * H + 2];
            ae3 += xv * weh_s[k * H + 3];
        }
        float ev[H];
        ev[0] = as1.x + ad1.x + ae0;
        ev[1] = as1.y + ad1.y + ae1;
        ev[2] = as1.z + ad1.z + ae2;
        ev[3] = as1.w + ad1.w + ae3;
#pragma unroll
        for (int h = 0; h < H; ++h) {
            float t = ev[h];
            t = t > 0.f ? t : NEG_SLOPE * t;
            ev[h] = __expf(t);
        }
        ExPack p;
        p.h = (f16x4){(f16)ev[0], (f16)ev[1], (f16)ev[2], (f16)ev[3]};
        evp[e1] = p.f;
        rank[e1] = r1;
    }
}

// ---------------- K2b: scan, block partial sums (1024 elems / block)
__global__ __launch_bounds__(256) void k_scan_partial(
    const int* __restrict__ deg, int* __restrict__ partial, int N) {
    __shared__ int sdata[256];
    int t = threadIdx.x;
    int base = blockIdx.x * 1024 + t * 4;
    int s = 0;
    if (base + 3 < N) {
        int4 v4 = *(const int4*)(deg + base);
        s = v4.x + v4.y + v4.z + v4.w;
    } else {
#pragma unroll
        for (int j = 0; j < 4; ++j) { int i = base + j; if (i < N) s += deg[i]; }
    }
    sdata[t] = s;
    __syncthreads();
    for (int off = 128; off > 0; off >>= 1) {
        if (t < off) sdata[t] += sdata[t + off];
        __syncthreads();
    }
    if (t == 0) partial[blockIdx.x] = sdata[0];
}

// ---------------- K2c: scan top level (single block), exclusive over partials
__global__ __launch_bounds__(256) void k_scan_top(
    int* __restrict__ partial, int* __restrict__ offs, int nb, int N) {
    __shared__ int sdata[256];
    int t = threadIdx.x;
    int v = (t < nb) ? partial[t] : 0;
    sdata[t] = v;
    __syncthreads();
    for (int off = 1; off < 256; off <<= 1) {
        int add = (t >= off) ? sdata[t - off] : 0;
        __syncthreads();
        sdata[t] += add;
        __syncthreads();
    }
    int excl = (t == 0) ? 0 : sdata[t - 1];
    if (t < nb) partial[t] = excl;
    if (t == nb - 1) offs[N] = sdata[t];   // total = E
}

// ---------------- K2d: final scan; offs aliases deg (in-place, block-local)
__global__ __launch_bounds__(256) void k_scan_final(
    int* __restrict__ deg_offs, const int* __restrict__ partial, int N) {
    __shared__ int sdata[256];
    int t = threadIdx.x;
    int base = blockIdx.x * 1024 + t * 4;
    int v[4]; int s = 0;
    if (base + 3 < N) {
        int4 v4 = *(const int4*)(deg_offs + base);
        v[0] = v4.x; v[1] = v4.y; v[2] = v4.z; v[3] = v4.w;
        s = v[0] + v[1] + v[2] + v[3];
    } else {
#pragma unroll
        for (int j = 0; j < 4; ++j) { int i = base + j; v[j] = (i < N) ? deg_offs[i] : 0; s += v[j]; }
    }
    sdata[t] = s;
    __syncthreads();
    for (int off = 1; off < 256; off <<= 1) {
        int add = (t >= off) ? sdata[t - off] : 0;
        __syncthreads();
        sdata[t] += add;
        __syncthreads();
    }
    int excl = partial[blockIdx.x] + ((t == 0) ? 0 : sdata[t - 1]);
    if (base + 3 < N) {
        int4 w;
        w.x = excl;
        w.y = excl + v[0];
        w.z = excl + v[0] + v[1];
        w.w = excl + v[0] + v[1] + v[2];
        *(int4*)(deg_offs + base) = w;
    } else {
#pragma unroll
        for (int j = 0; j < 4; ++j) {
            int i = base + j;
            if (i < N) { deg_offs[i] = excl; excl += v[j]; }
        }
    }
}

// ---------------- K3: pure permutation into dst-bucketed 16B records
__global__ __launch_bounds__(256) void k_permute(
    const int* __restrict__ src, const int* __restrict__ dst,
    const int* __restrict__ rank, const float2* __restrict__ evp,
    const int* __restrict__ offs, float4* __restrict__ rec, int E) {
    int base = blockIdx.x * 1024 + threadIdx.x;
    int s[4], d[4], r[4]; float2 q[4]; bool v[4];
#pragma unroll
    for (int j = 0; j < 4; ++j) {
        int e = base + j * 256;
        v[j] = e < E;
        s[j] = v[j] ? src[e] : 0;
        d[j] = v[j] ? dst[e] : 0;
        r[j] = v[j] ? rank[e] : 0;
        q[j] = v[j] ? evp[e] : make_float2(0.f, 0.f);
    }
    int pos[4];
#pragma unroll
    for (int j = 0; j < 4; ++j) pos[j] = offs[d[j]] + r[j];
#pragma unroll
    for (int j = 0; j < 4; ++j) {
        if (!v[j]) continue;
        float4 rr;
        rr.x = __int_as_float(s[j]);
        rr.y = q[j].x;
        rr.z = q[j].y;
        rr.w = 0.f;
        rec[pos[j]] = rr;
    }
}

// ---------------- K4: per-dst aggregation; wave/node, lane = 2 adjacent cols.
// fdot2 math; 8/4/1 edge loops. res16 path: read f16 residual, write-only out.
__device__ __forceinline__ unsigned ex16(float a, float b, int hword, int hshift) {
    unsigned u = __float_as_uint(hword ? b : a);
    return (u >> hshift) & 0xffffu;          // -> v_bfe_u32
}
__device__ __forceinline__ f16x2 u2h(unsigned u) {
    f16x2 h; __builtin_memcpy(&h, &u, 4); return h;
}
__device__ __forceinline__ float fdot2f(unsigned a, unsigned b, float c) {
#if defined(__has_builtin) && __has_builtin(__builtin_amdgcn_fdot2)
    return __builtin_amdgcn_fdot2(u2h(a), u2h(b), c, false);
#else
    f16x2 ha = u2h(a), hb = u2h(b);
    return c + (float)ha[0] * (float)hb[0] + (float)ha[1] * (float)hb[1];
#endif
}

__global__ __launch_bounds__(256) void k_aggr(
    const f16* __restrict__ feat16, const float4* __restrict__ rec,
    const int* __restrict__ offs, const f16* __restrict__ res16,
    float* __restrict__ out, int N) {
    int wave = threadIdx.x >> 6;
    int lane = threadIdx.x & 63;
    int n = blockIdx.x * 4 + wave;
    if (n >= N) return;
    int beg = offs[n], end = offs[n + 1];
    unsigned c0 = (unsigned)(lane << 1);    // 2 adjacent cols
    size_t o = (size_t)n * HD + c0;
    if (end <= beg) {                       // no in-edges: out = res (+bias)
        if (res16) {
            f16x2 rh = *(const f16x2*)(res16 + o);
            float2 v;
            v.x = (float)rh.x;
            v.y = (float)rh.y;
            *(float2*)(out + o) = v;
        }
        return;                             // null path: out pre-filled by GEMM
    }
    int hword = (lane >> 5) & 1;            // which packed float holds our f16
    int hshift = ((lane >> 4) & 1) * 16;    // which half of it
    const unsigned uones = 0x3C003C00u;     // f16x2 (1.0, 1.0)
    float num0 = 0.f, num1 = 0.f, den = 0.f;
    int i = beg;
    for (; i + 7 < end; i += 8) {
        float4 r[8];
#pragma unroll
        for (int k = 0; k < 8; ++k) r[k] = rec[i + k];
        unsigned f[8];
#pragma unroll
        for (int k = 0; k < 8; ++k)
            f[k] = *(const unsigned*)(feat16 + (((unsigned)__float_as_int(r[k].x) << 7) | c0));
#pragma unroll
        for (int k = 0; k < 8; k += 2) {
            unsigned epk = ex16(r[k].y, r[k].z, hword, hshift) |
                           (ex16(r[k + 1].y, r[k + 1].z, hword, hshift) << 16);
            unsigned xpk = __builtin_amdgcn_perm(f[k + 1], f[k], 0x05040100u);
            unsigned ypk = __builtin_amdgcn_perm(f[k + 1], f[k], 0x07060302u);
            num0 = fdot2f(epk, xpk, num0);
            num1 = fdot2f(epk, ypk, num1);
            den  = fdot2f(epk, uones, den);
        }
    }
    for (; i + 3 < end; i += 4) {
        float4 r0 = rec[i], r1 = rec[i + 1], r2 = rec[i + 2], r3 = rec[i + 3];
        unsigned f0 = *(const unsigned*)(feat16 + (((unsigned)__float_as_int(r0.x) << 7) | c0));
        unsigned f1 = *(const unsigned*)(feat16 + (((unsigned)__float_as_int(r1.x) << 7) | c0));
        unsigned f2 = *(const unsigned*)(feat16 + (((unsigned)__float_as_int(r2.x) << 7) | c0));
        unsigned f3 = *(const unsigned*)(feat16 + (((unsigned)__float_as_int(r3.x) << 7) | c0));
        unsigned e01 = ex16(r0.y, r0.z, hword, hshift) | (ex16(r1.y, r1.z, hword, hshift) << 16);
        unsigned e23 = ex16(r2.y, r2.z, hword, hshift) | (ex16(r3.y, r3.z, hword, hshift) << 16);
        unsigned x01 = __builtin_amdgcn_perm(f1, f0, 0x05040100u);
        unsigned y01 = __builtin_amdgcn_perm(f1, f0, 0x07060302u);
        unsigned x23 = __builtin_amdgcn_perm(f3, f2, 0x05040100u);
        unsigned y23 = __builtin_amdgcn_perm(f3, f2, 0x07060302u);
        num0 = fdot2f(e01, x01, num0);
        num1 = fdot2f(e01, y01, num1);
        num0 = fdot2f(e23, x23, num0);
        num1 = fdot2f(e23, y23, num1);
        den  = fdot2f(e01, uones, den);
        den  = fdot2f(e23, uones, den);
    }
    for (; i < end; ++i) {
        float4 r0 = rec[i];
        unsigned f0 = *(const unsigned*)(feat16 + (((unsigned)__float_as_int(r0.x) << 7) | c0));
        float e0 = (float)u2h(ex16(r0.y, r0.z, hword, hshift))[0];
        f16x2 fh = u2h(f0);
        num0 += e0 * (float)fh[0];
        num1 += e0 * (float)fh[1];
        den += e0;
    }
    float inv = 1.f / den;
    if (res16) {
        f16x2 rh = *(const f16x2*)(res16 + o);
        float2 v;
        v.x = num0 * inv + (float)rh.x;
        v.y = num1 * inv + (float)rh.y;
        *(float2*)(out + o) = v;
    } else {
        float2 v = *(float2*)(out + o);
        v.x += num0 * inv;
        v.y += num1 * inv;
        *(float2*)(out + o) = v;
    }
}

extern "C" void kernel_launch(void* const* d_in, const int* in_sizes, int n_in,
                              void* d_out, int out_size, void* d_ws, size_t ws_size,
                              hipStream_t stream) {
    const float* node_inputs = (const float*)d_in[0];
    const float* edge_inputs = (const float*)d_in[1];
    const int*   src         = (const int*)d_in[2];
    const int*   dst         = (const int*)d_in[3];
    const float* W_fc        = (const float*)d_in[4];
    const float* attn_src_p  = (const float*)d_in[5];
    const float* attn_dst_p  = (const float*)d_in[6];
    const float* W_edge      = (const float*)d_in[7];
    const float* attn_edge_p = (const float*)d_in[8];
    const float* W_res       = (const float*)d_in[9];
    const float* bias_p      = (const float*)d_in[10];

    int N = in_sizes[0] / NNODES_FEAT;   // 100000
    int E = in_sizes[2];                 // 1600000

    float* out = (float*)d_out;

    // ---- workspace layout (rec 16B-aligned by construction) ----
    f16*    feat16  = (f16*)d_ws;                          // N*128 halves
    float4* rec     = (float4*)(feat16 + (size_t)N * HD);  // E * 16B
    f16*    Wt      = (f16*)(rec + (size_t)E);             // 256*128 halves
    float*  a_src   = (float*)(Wt + 256 * 128);            // N*4
    float*  a_dst   = a_src + (size_t)N * H;               // N*4
    float*  w_eh    = a_dst + (size_t)N * H;               // 64
    int*    deg     = (int*)(w_eh + 64);                   // N+2 (becomes offs)
    int*    offs    = deg;                                 // alias
    int*    partial = deg + (N + 2);                       // 128
    int*    rank    = partial + 128;                       // E ints
    float2* evp     = (float2*)(rank + (size_t)E);         // E * 8B
    f16*    res16   = (f16*)(evp + (size_t)E);             // N*128 halves (optional)
    size_t need = (size_t)((char*)(res16 + (size_t)N * HD) - (char*)d_ws);
    if (need > ws_size) res16 = nullptr;   // fall back to fp32 out RMW path

    hipMemsetAsync(deg, 0, (size_t)(N + 2) * sizeof(int), stream);

    // precompute small tensors
    k_wedge<<<1, 64, 0, stream>>>(W_edge, attn_edge_p, w_eh);
    k_wt<<<(256 * 128) / 256, 256, 0, stream>>>(W_fc, W_res, Wt);

    // MFMA GEMM (no LDS, no barriers) -> feat16 + a_src/a_dst, res16 or out
    int gb = (N + 63) / 64;
    k_gemm_mfma<<<gb, 256, 0, stream>>>(node_inputs, Wt, bias_p, attn_src_p,
                                        attn_dst_p, feat16, a_src, a_dst,
                                        res16, out, N);

    // count + rank + full per-edge logit/exp (edge-ordered evp), 2 edges/thread
    int eb = (E + 511) / 512;
    k_edge_logit<<<eb, 256, 0, stream>>>(edge_inputs, src, dst, w_eh, a_src, a_dst,
                                         deg, rank, evp, E);

    // scan deg -> offs
    int sb = (N + 1023) / 1024;   // 98 blocks
    k_scan_partial<<<sb, 256, 0, stream>>>(deg, partial, N);
    k_scan_top<<<1, 256, 0, stream>>>(partial, offs, sb, N);
    k_scan_final<<<sb, 256, 0, stream>>>(deg, partial, N);

    // permute into dst-bucketed records
    int pb = (E + 1023) / 1024;
    k_permute<<<pb, 256, 0, stream>>>(src, dst, rank, evp, offs, rec, E);

    // aggregation
    int ab = (N + 3) / 4;
    k_aggr<<<ab, 256, 0, stream>>>(feat16, rec, offs, res16, out, N);
}

// Round 12
// 436.002 us; speedup vs baseline: 1.0632x; 1.0632x over previous
//
#include <hip/hip_runtime.h>
#include <math.h>

#define NNODES_FEAT 128   // node input dim
#define HD 128            // H*D = 4*32
#define H 4
#define D 32
#define EDGE_F 16         // edge input dim
#define NEG_SLOPE 0.2f

typedef _Float16 f16;
typedef _Float16 f16x2 __attribute__((ext_vector_type(2)));
typedef _Float16 f16x4 __attribute__((ext_vector_type(4)));
typedef _Float16 f16x8 __attribute__((ext_vector_type(8)));
typedef float f32x4 __attribute__((ext_vector_type(4)));

union ExPack { float2 f; f16x4 h; };

// ---------------- K0: w_eh[k][h] = sum_d W_edge[k*128 + h*32 + d] * attn_edge[h*32+d]
__global__ void k_wedge(const float* __restrict__ W_edge,
                        const float* __restrict__ attn_edge,
                        float* __restrict__ w_eh) {
    int t = threadIdx.x;            // 0..63
    int k = t >> 2;                 // 0..15
    int h = t & 3;                  // 0..3
    float s = 0.f;
    for (int d = 0; d < D; ++d)
        s += W_edge[k * HD + h * D + d] * attn_edge[h * D + d];
    w_eh[k * H + h] = s;
}

// ---------------- K0c: Wt[n][k] = (n<128 ? Wfc[k][n] : Wres[k][n-128]) as fp16
__global__ __launch_bounds__(256) void k_wt(const float* __restrict__ Wfc,
                                            const float* __restrict__ Wres,
                                            f16* __restrict__ Wt) {
    int i = blockIdx.x * 256 + threadIdx.x;    // 0..32767
    int n = i >> 7, k = i & 127;
    float v = (n < 128) ? Wfc[k * HD + n] : Wres[k * HD + (n - 128)];
    Wt[(size_t)n * 128 + k] = (f16)v;
}

// ---------------- K1: MFMA GEMM. grid.y = cb half. B staged in LDS (34.8KB,
// ONE sync); A row fragment loaded per-lane direct from global into regs.
// cb=0 epilogue: feat16 + fused a_src/a_dst. cb=1: res16 (or fp32 out fallback).
#define LDK 136   // padded leading dim (halves)
__global__ __launch_bounds__(256) void k_gemm_mfma(
    const float* __restrict__ A, const f16* __restrict__ Wt,
    const float* __restrict__ bias, const float* __restrict__ asp,
    const float* __restrict__ adp, f16* __restrict__ feat16,
    float* __restrict__ a_src, float* __restrict__ a_dst,
    f16* __restrict__ res16, float* __restrict__ out, int N) {
    __shared__ f16 Bs[128 * LDK];
    int tid = threadIdx.x;
    int wave = tid >> 6, lane = tid & 63;
    int am = lane & 15, aq = lane >> 4;
    int cb = blockIdx.y;
    int gr = blockIdx.x * 64 + wave * 16 + am;     // this lane's A row
    int orow0 = blockIdx.x * 64 + wave * 16 + aq * 4;

    // stage B half: 128 rows x 128 halves (coalesced float4)
    const f16* Wblk = Wt + (size_t)cb * 128 * 128;
    for (int c = tid; c < 128 * 16; c += 256) {
        int r = c >> 4, cc = (c & 15) * 8;
        float4 v = *(const float4*)(Wblk + (size_t)r * 128 + cc);
        *(float4*)(&Bs[r * LDK + cc]) = v;
    }

    // A row fragment: 32 fp32 (cols kc*32 + aq*8 .. +8) -> f16x8 regs
    // (issued while B staging is in flight; no barrier dependency)
    f16x8 af[4];
    bool rowok = gr < N;
    const float* Arow = A + (size_t)gr * 128;
#pragma unroll
    for (int kc = 0; kc < 4; ++kc) {
        float4 lo = make_float4(0.f, 0.f, 0.f, 0.f), hi = lo;
        if (rowok) {
            lo = *(const float4*)(Arow + kc * 32 + aq * 8);
            hi = *(const float4*)(Arow + kc * 32 + aq * 8 + 4);
        }
        af[kc] = (f16x8){(f16)lo.x, (f16)lo.y, (f16)lo.z, (f16)lo.w,
                         (f16)hi.x, (f16)hi.y, (f16)hi.z, (f16)hi.w};
    }
    __syncthreads();   // the only barrier

    f32x4 acc[8];
#pragma unroll
    for (int nt = 0; nt < 8; ++nt) acc[nt] = (f32x4){0.f, 0.f, 0.f, 0.f};
#pragma unroll
    for (int kc = 0; kc < 4; ++kc) {
#pragma unroll
        for (int nt = 0; nt < 8; ++nt) {
            f16x8 b = *(const f16x8*)(&Bs[(nt * 16 + am) * LDK + kc * 32 + aq * 8]);
            acc[nt] = __builtin_amdgcn_mfma_f32_16x16x32_f16(af[kc], b, acc[nt], 0, 0, 0);
        }
    }

    if (cb == 0) {
        // feat16 store
#pragma unroll
        for (int nt = 0; nt < 8; ++nt) {
            int col = nt * 16 + am;
#pragma unroll
            for (int r = 0; r < 4; ++r) {
                int row = orow0 + r;
                if (row < N) feat16[(size_t)row * 128 + col] = (f16)acc[nt][r];
            }
        }
        // fused a_src/a_dst: per-lane partials over cols, xor-reduce over am
        float w1v[8], w2v[8];
#pragma unroll
        for (int nt = 0; nt < 8; ++nt) {
            w1v[nt] = asp[nt * 16 + am];
            w2v[nt] = adp[nt * 16 + am];
        }
#pragma unroll
        for (int r = 0; r < 4; ++r) {
            float p1[4] = {0.f, 0.f, 0.f, 0.f};
            float p2[4] = {0.f, 0.f, 0.f, 0.f};
#pragma unroll
            for (int nt = 0; nt < 8; ++nt) {
                int h = nt >> 1;
                p1[h] += acc[nt][r] * w1v[nt];
                p2[h] += acc[nt][r] * w2v[nt];
            }
#pragma unroll
            for (int off = 1; off < 16; off <<= 1) {
#pragma unroll
                for (int h = 0; h < 4; ++h) {
                    p1[h] += __shfl_xor(p1[h], off);
                    p2[h] += __shfl_xor(p2[h], off);
                }
            }
            int row = orow0 + r;
            if (row < N) {
                if (am < 4) {
                    float v = am == 0 ? p1[0] : am == 1 ? p1[1] : am == 2 ? p1[2] : p1[3];
                    a_src[row * 4 + am] = v;
                } else if (am < 8) {
                    int hh = am - 4;
                    float v = hh == 0 ? p2[0] : hh == 1 ? p2[1] : hh == 2 ? p2[2] : p2[3];
                    a_dst[row * 4 + hh] = v;
                }
            }
        }
    } else {
#pragma unroll
        for (int nt = 0; nt < 8; ++nt) {
            int col = nt * 16 + am;
            float bv = bias[col];
#pragma unroll
            for (int r = 0; r < 4; ++r) {
                int row = orow0 + r;
                if (row < N) {
                    float v = acc[nt][r] + bv;
                    if (res16) res16[(size_t)row * 128 + col] = (f16)v;
                    else       out[(size_t)row * 128 + col] = v;
                }
            }
        }
    }
}

// ---------------- K2a: count + rank + FULL edge logit -> exp -> evp[e] (edge order)
// 2 edges/thread; ALL loads (indices, MLP inputs, gathers) issued up front.
__global__ __launch_bounds__(256) void k_edge_logit(
    const float* __restrict__ edge_inputs, const int* __restrict__ src,
    const int* __restrict__ dst, const float* __restrict__ w_eh,
    const float* __restrict__ a_src, const float* __restrict__ a_dst,
    int* __restrict__ deg, int* __restrict__ rank,
    float2* __restrict__ evp, int E) {
    __shared__ float weh_s[EDGE_F * H];
    if (threadIdx.x < EDGE_F * H) weh_s[threadIdx.x] = w_eh[threadIdx.x];
    __syncthreads();

    int base = blockIdx.x * 512 + threadIdx.x;
    int e0 = base, e1 = base + 256;
    bool v0 = e0 < E, v1 = e1 < E;

    // coalesced index loads
    int s0 = v0 ? src[e0] : 0, s1 = v1 ? src[e1] : 0;
    int d0 = v0 ? dst[e0] : 0, d1 = v1 ? dst[e1] : 0;

    // MLP input loads (independent)
    float4 xa[4], xb[4];
    if (v0) {
        const float* x = edge_inputs + (size_t)e0 * EDGE_F;
        xa[0] = *(const float4*)(x);      xa[1] = *(const float4*)(x + 4);
        xa[2] = *(const float4*)(x + 8);  xa[3] = *(const float4*)(x + 12);
    }
    if (v1) {
        const float* x = edge_inputs + (size_t)e1 * EDGE_F;
        xb[0] = *(const float4*)(x);      xb[1] = *(const float4*)(x + 4);
        xb[2] = *(const float4*)(x + 8);  xb[3] = *(const float4*)(x + 12);
    }

    // L2-resident gathers
    float4 as0 = *(const float4*)(a_src + s0 * H);
    float4 ad0 = *(const float4*)(a_dst + d0 * H);
    float4 as1 = *(const float4*)(a_src + s1 * H);
    float4 ad1 = *(const float4*)(a_dst + d1 * H);

    int r0 = v0 ? atomicAdd(deg + d0, 1) : 0;
    int r1 = v1 ? atomicAdd(deg + d1, 1) : 0;

    if (v0) {
        float ae0 = 0.f, ae1 = 0.f, ae2 = 0.f, ae3 = 0.f;
        const float* xs = (const float*)xa;
#pragma unroll
        for (int k = 0; k < EDGE_F; ++k) {
            float xv = xs[k];
            ae0 += xv * weh_s[k * H + 0];
            ae1 += xv * weh_s[k * H + 1];
            ae2 += xv * weh_s[k * H + 2];
            ae3 += xv * weh_s[k * H + 3];
        }
        float ev[H];
        ev[0] = as0.x + ad0.x + ae0;
        ev[1] = as0.y + ad0.y + ae1;
        ev[2] = as0.z + ad0.z + ae2;
        ev[3] = as0.w + ad0.w + ae3;
#pragma unroll
        for (int h = 0; h < H; ++h) {
            float t = ev[h];
            t = t > 0.f ? t : NEG_SLOPE * t;
            ev[h] = __expf(t);
        }
        ExPack p;
        p.h = (f16x4){(f16)ev[0], (f16)ev[1], (f16)ev[2], (f16)ev[3]};
        evp[e0] = p.f;
        rank[e0] = r0;
    }
    if (v1) {
        float ae0 = 0.f, ae1 = 0.f, ae2 = 0.f, ae3 = 0.f;
        const float* xs = (const float*)xb;
#pragma unroll
        for (int k = 0; k < EDGE_F; ++k) {
            float xv = xs[k];
            ae0 += xv * weh_s[k * H + 0];
            ae1 += xv * weh_s[k * H + 1];
            ae2 += xv * weh_s[k * H + 2];
            ae3 += xv * weh_s[k * H + 3];
        }
        float ev[H];
        ev[0] = as1.x + ad1.x + ae0;
        ev[1] = as1.y + ad1.y + ae1;
        ev[2] = as1.z + ad1.z + ae2;
        ev[3] = as1.w + ad1.w + ae3;
#pragma unroll
        for (int h = 0; h < H; ++h) {
            float t = ev[h];
            t = t > 0.f ? t : NEG_SLOPE * t;
            ev[h] = __expf(t);
        }
        ExPack p;
        p.h = (f16x4){(f16)ev[0], (f16)ev[1], (f16)ev[2], (f16)ev[3]};
        evp[e1] = p.f;
        rank[e1] = r1;
    }
}

// ---------------- K2b: scan, block partial sums (1024 elems / block)
__global__ __launch_bounds__(256) void k_scan_partial(
    const int* __restrict__ deg, int* __restrict__ partial, int N) {
    __shared__ int sdata[256];
    int t = threadIdx.x;
    int base = blockIdx.x * 1024 + t * 4;
    int s = 0;
    if (base + 3 < N) {
        int4 v4 = *(const int4*)(deg + base);
        s = v4.x + v4.y + v4.z + v4.w;
    } else {
#pragma unroll
        for (int j = 0; j < 4; ++j) { int i = base + j; if (i < N) s += deg[i]; }
    }
    sdata[t] = s;
    __syncthreads();
    for (int off = 128; off > 0; off >>= 1) {
        if (t < off) sdata[t] += sdata[t + off];
        __syncthreads();
    }
    if (t == 0) partial[blockIdx.x] = sdata[0];
}

// ---------------- K2c: scan top level (single block), exclusive over partials
__global__ __launch_bounds__(256) void k_scan_top(
    int* __restrict__ partial, int* __restrict__ offs, int nb, int N) {
    __shared__ int sdata[256];
    int t = threadIdx.x;
    int v = (t < nb) ? partial[t] : 0;
    sdata[t] = v;
    __syncthreads();
    for (int off = 1; off < 256; off <<= 1) {
        int add = (t >= off) ? sdata[t - off] : 0;
        __syncthreads();
        sdata[t] += add;
        __syncthreads();
    }
    int excl = (t == 0) ? 0 : sdata[t - 1];
    if (t < nb) partial[t] = excl;
    if (t == nb - 1) offs[N] = sdata[t];   // total = E
}

// ---------------- K2d: final scan; offs aliases deg (in-place, block-local)
__global__ __launch_bounds__(256) void k_scan_final(
    int* __restrict__ deg_offs, const int* __restrict__ partial, int N) {
    __shared__ int sdata[256];
    int t = threadIdx.x;
    int base = blockIdx.x * 1024 + t * 4;
    int v[4]; int s = 0;
    if (base + 3 < N) {
        int4 v4 = *(const int4*)(deg_offs + base);
        v[0] = v4.x; v[1] = v4.y; v[2] = v4.z; v[3] = v4.w;
        s = v[0] + v[1] + v[2] + v[3];
    } else {
#pragma unroll
        for (int j = 0; j < 4; ++j) { int i = base + j; v[j] = (i < N) ? deg_offs[i] : 0; s += v[j]; }
    }
    sdata[t] = s;
    __syncthreads();
    for (int off = 1; off < 256; off <<= 1) {
        int add = (t >= off) ? sdata[t - off] : 0;
        __syncthreads();
        sdata[t] += add;
        __syncthreads();
    }
    int excl = partial[blockIdx.x] + ((t == 0) ? 0 : sdata[t - 1]);
    if (base + 3 < N) {
        int4 w;
        w.x = excl;
        w.y = excl + v[0];
        w.z = excl + v[0] + v[1];
        w.w = excl + v[0] + v[1] + v[2];
        *(int4*)(deg_offs + base) = w;
    } else {
#pragma unroll
        for (int j = 0; j < 4; ++j) {
            int i = base + j;
            if (i < N) { deg_offs[i] = excl; excl += v[j]; }
        }
    }
}

// ---------------- K3: pure permutation into dst-bucketed 16B records
__global__ __launch_bounds__(256) void k_permute(
    const int* __restrict__ src, const int* __restrict__ dst,
    const int* __restrict__ rank, const float2* __restrict__ evp,
    const int* __restrict__ offs, float4* __restrict__ rec, int E) {
    int base = blockIdx.x * 1024 + threadIdx.x;
    int s[4], d[4], r[4]; float2 q[4]; bool v[4];
#pragma unroll
    for (int j = 0; j < 4; ++j) {
        int e = base + j * 256;
        v[j] = e < E;
        s[j] = v[j] ? src[e] : 0;
        d[j] = v[j] ? dst[e] : 0;
        r[j] = v[j] ? rank[e] : 0;
        q[j] = v[j] ? evp[e] : make_float2(0.f, 0.f);
    }
    int pos[4];
#pragma unroll
    for (int j = 0; j < 4; ++j) pos[j] = offs[d[j]] + r[j];
#pragma unroll
    for (int j = 0; j < 4; ++j) {
        if (!v[j]) continue;
        float4 rr;
        rr.x = __int_as_float(s[j]);
        rr.y = q[j].x;
        rr.z = q[j].y;
        rr.w = 0.f;
        rec[pos[j]] = rr;
    }
}

// ---------------- K4: per-dst aggregation; wave/node, lane = 2 adjacent cols.
// fdot2 math; 8/4/1 edge loops. res16 path: read f16 residual, write-only out.
__device__ __forceinline__ unsigned ex16(float a, float b, int hword, int hshift) {
    unsigned u = __float_as_uint(hword ? b : a);
    return (u >> hshift) & 0xffffu;          // -> v_bfe_u32
}
__device__ __forceinline__ f16x2 u2h(unsigned u) {
    f16x2 h; __builtin_memcpy(&h, &u, 4); return h;
}
__device__ __forceinline__ float fdot2f(unsigned a, unsigned b, float c) {
#if defined(__has_builtin) && __has_builtin(__builtin_amdgcn_fdot2)
    return __builtin_amdgcn_fdot2(u2h(a), u2h(b), c, false);
#else
    f16x2 ha = u2h(a), hb = u2h(b);
    return c + (float)ha[0] * (float)hb[0] + (float)ha[1] * (float)hb[1];
#endif
}

__global__ __launch_bounds__(256) void k_aggr(
    const f16* __restrict__ feat16, const float4* __restrict__ rec,
    const int* __restrict__ offs, const f16* __restrict__ res16,
    float* __restrict__ out, int N) {
    int wave = threadIdx.x >> 6;
    int lane = threadIdx.x & 63;
    int n = blockIdx.x * 4 + wave;
    if (n >= N) return;
    int beg = offs[n], end = offs[n + 1];
    unsigned c0 = (unsigned)(lane << 1);    // 2 adjacent cols
    size_t o = (size_t)n * HD + c0;
    if (end <= beg) {                       // no in-edges: out = res (+bias)
        if (res16) {
            f16x2 rh = *(const f16x2*)(res16 + o);
            float2 v;
            v.x = (float)rh.x;
            v.y = (float)rh.y;
            *(float2*)(out + o) = v;
        }
        return;                             // null path: out pre-filled by GEMM
    }
    int hword = (lane >> 5) & 1;            // which packed float holds our f16
    int hshift = ((lane >> 4) & 1) * 16;    // which half of it
    const unsigned uones = 0x3C003C00u;     // f16x2 (1.0, 1.0)
    float num0 = 0.f, num1 = 0.f, den = 0.f;
    int i = beg;
    for (; i + 7 < end; i += 8) {
        float4 r[8];
#pragma unroll
        for (int k = 0; k < 8; ++k) r[k] = rec[i + k];
        unsigned f[8];
#pragma unroll
        for (int k = 0; k < 8; ++k)
            f[k] = *(const unsigned*)(feat16 + (((unsigned)__float_as_int(r[k].x) << 7) | c0));
#pragma unroll
        for (int k = 0; k < 8; k += 2) {
            unsigned epk = ex16(r[k].y, r[k].z, hword, hshift) |
                           (ex16(r[k + 1].y, r[k + 1].z, hword, hshift) << 16);
            unsigned xpk = __builtin_amdgcn_perm(f[k + 1], f[k], 0x05040100u);
            unsigned ypk = __builtin_amdgcn_perm(f[k + 1], f[k], 0x07060302u);
            num0 = fdot2f(epk, xpk, num0);
            num1 = fdot2f(epk, ypk, num1);
            den  = fdot2f(epk, uones, den);
        }
    }
    for (; i + 3 < end; i += 4) {
        float4 r0 = rec[i], r1 = rec[i + 1], r2 = rec[i + 2], r3 = rec[i + 3];
        unsigned f0 = *(const unsigned*)(feat16 + (((unsigned)__float_as_int(r0.x) << 7) | c0));
        unsigned f1 = *(const unsigned*)(feat16 + (((unsigned)__float_as_int(r1.x) << 7) | c0));
        unsigned f2 = *(const unsigned*)(feat16 + (((unsigned)__float_as_int(r2.x) << 7) | c0));
        unsigned f3 = *(const unsigned*)(feat16 + (((unsigned)__float_as_int(r3.x) << 7) | c0));
        unsigned e01 = ex16(r0.y, r0.z, hword, hshift) | (ex16(r1.y, r1.z, hword, hshift) << 16);
        unsigned e23 = ex16(r2.y, r2.z, hword, hshift) | (ex16(r3.y, r3.z, hword, hshift) << 16);
        unsigned x01 = __builtin_amdgcn_perm(f1, f0, 0x05040100u);
        unsigned y01 = __builtin_amdgcn_perm(f1, f0, 0x07060302u);
        unsigned x23 = __builtin_amdgcn_perm(f3, f2, 0x05040100u);
        unsigned y23 = __builtin_amdgcn_perm(f3, f2, 0x07060302u);
        num0 = fdot2f(e01, x01, num0);
        num1 = fdot2f(e01, y01, num1);
        num0 = fdot2f(e23, x23, num0);
        num1 = fdot2f(e23, y23, num1);
        den  = fdot2f(e01, uones, den);
        den  = fdot2f(e23, uones, den);
    }
    for (; i < end; ++i) {
        float4 r0 = rec[i];
        unsigned f0 = *(const unsigned*)(feat16 + (((unsigned)__float_as_int(r0.x) << 7) | c0));
        float e0 = (float)u2h(ex16(r0.y, r0.z, hword, hshift))[0];
        f16x2 fh = u2h(f0);
        num0 += e0 * (float)fh[0];
        num1 += e0 * (float)fh[1];
        den += e0;
    }
    float inv = 1.f / den;
    if (res16) {
        f16x2 rh = *(const f16x2*)(res16 + o);
        float2 v;
        v.x = num0 * inv + (float)rh.x;
        v.y = num1 * inv + (float)rh.y;
        *(float2*)(out + o) = v;
    } else {
        float2 v = *(float2*)(out + o);
        v.x += num0 * inv;
        v.y += num1 * inv;
        *(float2*)(out + o) = v;
    }
}

extern "C" void kernel_launch(void* const* d_in, const int* in_sizes, int n_in,
                              void* d_out, int out_size, void* d_ws, size_t ws_size,
                              hipStream_t stream) {
    const float* node_inputs = (const float*)d_in[0];
    const float* edge_inputs = (const float*)d_in[1];
    const int*   src         = (const int*)d_in[2];
    const int*   dst         = (const int*)d_in[3];
    const float* W_fc        = (const float*)d_in[4];
    const float* attn_src_p  = (const float*)d_in[5];
    const float* attn_dst_p  = (const float*)d_in[6];
    const float* W_edge      = (const float*)d_in[7];
    const float* attn_edge_p = (const float*)d_in[8];
    const float* W_res       = (const float*)d_in[9];
    const float* bias_p      = (const float*)d_in[10];

    int N = in_sizes[0] / NNODES_FEAT;   // 100000
    int E = in_sizes[2];                 // 1600000

    float* out = (float*)d_out;

    // ---- workspace layout (rec 16B-aligned by construction) ----
    f16*    feat16  = (f16*)d_ws;                          // N*128 halves
    float4* rec     = (float4*)(feat16 + (size_t)N * HD);  // E * 16B
    f16*    Wt      = (f16*)(rec + (size_t)E);             // 256*128 halves
    float*  a_src   = (float*)(Wt + 256 * 128);            // N*4
    float*  a_dst   = a_src + (size_t)N * H;               // N*4
    float*  w_eh    = a_dst + (size_t)N * H;               // 64
    int*    deg     = (int*)(w_eh + 64);                   // N+2 (becomes offs)
    int*    offs    = deg;                                 // alias
    int*    partial = deg + (N + 2);                       // 128
    int*    rank    = partial + 128;                       // E ints
    float2* evp     = (float2*)(rank + (size_t)E);         // E * 8B
    f16*    res16   = (f16*)(evp + (size_t)E);             // N*128 halves (optional)
    size_t need = (size_t)((char*)(res16 + (size_t)N * HD) - (char*)d_ws);
    if (need > ws_size) res16 = nullptr;   // fall back to fp32 out RMW path

    hipMemsetAsync(deg, 0, (size_t)(N + 2) * sizeof(int), stream);

    // precompute small tensors
    k_wedge<<<1, 64, 0, stream>>>(W_edge, attn_edge_p, w_eh);
    k_wt<<<(256 * 128) / 256, 256, 0, stream>>>(W_fc, W_res, Wt);

    // MFMA GEMM (B in LDS, A in regs, one barrier, grid.y = cb)
    dim3 g1((N + 63) / 64, 2);
    k_gemm_mfma<<<g1, 256, 0, stream>>>(node_inputs, Wt, bias_p, attn_src_p,
                                        attn_dst_p, feat16, a_src, a_dst,
                                        res16, out, N);

    // count + rank + full per-edge logit/exp (edge-ordered evp), 2 edges/thread
    int eb = (E + 511) / 512;
    k_edge_logit<<<eb, 256, 0, stream>>>(edge_inputs, src, dst, w_eh, a_src, a_dst,
                                         deg, rank, evp, E);

    // scan deg -> offs
    int sb = (N + 1023) / 1024;   // 98 blocks
    k_scan_partial<<<sb, 256, 0, stream>>>(deg, partial, N);
    k_scan_top<<<1, 256, 0, stream>>>(partial, offs, sb, N);
    k_scan_final<<<sb, 256, 0, stream>>>(deg, partial, N);

    // permute into dst-bucketed records
    int pb = (E + 1023) / 1024;
    k_permute<<<pb, 256, 0, stream>>>(src, dst, rank, evp, offs, rec, E);

    // aggregation
    int ab = (N + 3) / 4;
    k_aggr<<<ab, 256, 0, stream>>>(feat16, rec, offs, res16, out, N);
}